// Round 27
// baseline (1679.480 us; speedup 1.0000x reference)
//
#include <hip/hip_runtime.h>

// ---------------------------------------------------------------------------
// VanillaRNN on MI355X (gfx950)   [R27 = R26 (measured 1632us) + two small
//                                  levers: out_gemm 512->1024 WGs (4/CU) and
//                                  rnn_seq MFMA 2->4 accumulator chains]
// B=128, S=1024, H=1024, E=512, V=256
//
//  rnn_seq core (R25/R26-proven): tile h2 layout, 4-wave K-split, LDS
//  reduce, sc0/nt L2 flags, fast_tanh, t+2 pre-touch (write-no-allocate
//  store-misses -> L2 store-hits; drain ack + consumer read L2-served).
//  Measured: 1.53us/step, FETCH 144MB, WRITE 262MB.
// ---------------------------------------------------------------------------

typedef __attribute__((ext_vector_type(8))) short bhalf8;   // 8 bf16 (4 VGPR)
typedef __attribute__((ext_vector_type(4))) float floatx4;  // 4 f32

typedef unsigned short u16;
typedef unsigned int u32;

#define B_  128
#define S_  1024
#define H_  1024
#define E_  512
#define V_  256

// h2 addressing (u16 units): idx(t,g,ws) = t*131072 + g*16384 + ws*512
#define T_STRIDE   131072        // 256KB / 2
#define G_STRIDE   16384         // 32KB / 2
#define WS_STRIDE  512           // 1KB / 2

// ws layout (bytes)
#define WHH_OFF       (268697600ull)            // h2: 1025*262144
#define WHO_OFF       (WHH_OFF + 2097152ull)
#define PROJ_OFF      (WHO_OFF + 524288ull)
#define CNT_OFF       (PROJ_OFF + 1048576ull)

#define FLAG_STRIDE   16                        // ints (64 B)
#define NFLAGS        4096
#define SPIN_CAP      16384                     // bounded spin: fail-loud

__device__ inline u16 f2bf(float f) {
    u32 u = __builtin_bit_cast(u32, f);
    u32 lsb = (u >> 16) & 1u;
    u += 0x7fffu + lsb;
    return (u16)(u >> 16);
}
__device__ inline float bf2f(u16 h) {
    u32 u = ((u32)h) << 16;
    return __builtin_bit_cast(float, u);
}
__device__ inline bhalf8 ld8(const u16* p) {
    return *(const bhalf8*)p;
}

// fast tanh: 1 - 2/(e^{2x}+1), e^{2x} = 2^{2*log2(e)*x}.
__device__ inline float fast_tanh(float x) {
    float t = __builtin_amdgcn_exp2f(2.885390082f * x);
    return 1.0f - 2.0f * __builtin_amdgcn_rcpf(t + 1.0f);
}

// Flag transport at the XCD's shared L2 (R11-proven):
__device__ inline int poll_flag_l2(const int* p) {
    int v;
    asm volatile("global_load_dword %0, %1, off sc0 nt\n\ts_waitcnt vmcnt(0)"
                 : "=v"(v) : "v"(p) : "memory");
    return v;
}
__device__ inline void publish_flag_l2(int* p, int v) {
    asm volatile("global_store_dword %0, %1, off sc0"
                 :: "v"(p), "v"(v) : "memory");
}

// ---------------------------------------------------------------------------
// 1. prep
// ---------------------------------------------------------------------------
__global__ __launch_bounds__(256) void prep_kernel(
    const float* __restrict__ W_hh, const float* __restrict__ W_ho,
    const float* __restrict__ hidden,
    u16* __restrict__ Whh_bf, u16* __restrict__ Who_bf,
    u16* __restrict__ h2, int* __restrict__ cnt)
{
    int i = blockIdx.x * 256 + threadIdx.x;
    if (i < 1048576) {
        Whh_bf[i] = f2bf(W_hh[i]);
    } else if (i < 1048576 + 262144) {
        int j = i - 1048576;
        Who_bf[j] = f2bf(W_ho[j]);
    } else if (i < 1048576 + 262144 + 131072) {
        int j = i - (1048576 + 262144);
        int b = j >> 10, k = j & 1023;
        int g = b >> 4, r = b & 15, ws = k >> 5, c = k & 31;
        h2[g * G_STRIDE + ws * WS_STRIDE + r * 32 + c] = f2bf(hidden[j]);
    } else if (i < 1048576 + 262144 + 131072 + NFLAGS) {
        cnt[i - (1048576 + 262144 + 131072)] = 0;
    }
}

// ---------------------------------------------------------------------------
// 2. proj table: proj[v][h] = b_ih[h] + b_hh[h] + sum_e emb[v][e]*W_ih[h][e]
// ---------------------------------------------------------------------------
__global__ __launch_bounds__(256) void proj_kernel(
    const float* __restrict__ emb, const float* __restrict__ W_ih,
    const float* __restrict__ b_ih, const float* __restrict__ b_hh,
    float* __restrict__ proj)
{
    __shared__ float er[E_];
    int v = blockIdx.x, tid = threadIdx.x;
    er[tid]       = emb[v * E_ + tid];
    er[tid + 256] = emb[v * E_ + 256 + tid];
    __syncthreads();
    const float4* x = (const float4*)er;
    #pragma unroll
    for (int j = 0; j < 4; ++j) {
        int hc = tid + j * 256;
        const float4* w = (const float4*)&W_ih[(size_t)hc * E_];
        float s = 0.f;
        #pragma unroll 8
        for (int e = 0; e < E_ / 4; ++e) {
            float4 ww = w[e]; float4 xx = x[e];
            s += ww.x * xx.x + ww.y * xx.y + ww.z * xx.z + ww.w * xx.w;
        }
        proj[v * H_ + hc] = s + b_ih[hc] + b_hh[hc];
    }
}

// ---------------------------------------------------------------------------
// 3. persistent sequential RNN kernel  (R26 + 4-chain MFMA ILP)
//    grid = 256 WGs x 256 threads. group g = wg&7 (XCD), 32 WGs/group,
//    WG owns 32 h-cols; 4 waves split K=1024; LDS reduce; tile store.
// ---------------------------------------------------------------------------
__global__ __launch_bounds__(256) void rnn_seq(
    const int* __restrict__ seq, const float* __restrict__ proj,
    const u16* __restrict__ Whh, u16* __restrict__ h2,
    int* __restrict__ cnt)
{
    const int wg = blockIdx.x;
    const int g = wg & 7;
    const int wslot = wg >> 3;          // 0..31 within group
    const int colbase = wslot * 32;
    const int tid = threadIdx.x;
    const int wave = tid >> 6;
    const int lane = tid & 63;
    const int l16 = lane & 15, lq = lane >> 4;
    const int kb = wave * 256;          // wave's K-slice base

    // W_hh slice resident in registers: 2 col-tiles x 8 k-steps
    bhalf8 bfrag[2][8];
    #pragma unroll
    for (int tt = 0; tt < 2; ++tt) {
        #pragma unroll
        for (int ks = 0; ks < 8; ++ks) {
            bfrag[tt][ks] = ld8(&Whh[(size_t)(colbase + tt * 16 + l16) * H_
                                     + kb + ks * 32 + lq * 8]);
        }
    }

    __shared__ float red[4][2][16][17];   // [wave][tile][row][col+pad]

    int* gflags = cnt + g * 32 * FLAG_STRIDE;
    int* myflag = gflags + wslot * FLAG_STRIDE;
    // wave w consumes h cols [w*256, w*256+256) = wslots [w*8, w*8+8)
    int* pollp  = gflags + (wave * 8 + (lane & 7)) * FLAG_STRIDE;

    // A-frag source: tile (t, g, wave*8+ks), lane offset l16*32 + lq*8
    const int aLane = g * G_STRIDE + wave * 8 * WS_STRIDE + l16 * 32 + lq * 8;

    // reduce-phase fixed indices (coalesced tile stores):
    const int row = tid >> 4;           // batch row within group (0..15)
    const int cp  = tid & 15;           // col pair (cols 2cp, 2cp+1)
    const int c0 = 2 * cp, c1 = c0 + 1;
    const int sLane = g * G_STRIDE + wslot * WS_STRIDE + row * 32 + cp * 2;
    const int seqBase = (g * 16 + row) * S_;

    // pre-touch target: 128B line `lane` (0..7) of this WG's output tile
    const int touchLane = g * G_STRIDE + wslot * WS_STRIDE + lane * 64;

    for (int t = 0; t < S_; ++t) {
        // early load (independent of h): token
        int tok = seq[seqBase + t];

        // --- pre-touch own output lines for step t+2 (stored at step t+1,
        //     ~5800cy from now -> fill guaranteed complete; no race). The
        //     allocation makes the t+1 store an L2 HIT. Discarded result;
        //     keep-alive after sync1 (waitcnt covered by MFMA+LDS work). ---
        u32 touch_dummy = 0;
        if (wave == 0 && lane < 8 && t < S_ - 1) {
            const u16* tp = h2 + (size_t)(t + 2) * T_STRIDE + touchLane;
            asm volatile("global_load_dword %0, %1, off"
                         : "=v"(touch_dummy) : "v"(tp) : "memory");
        }

        // --- MFMA: z_partial[16 x 32], 4 independent accumulator chains
        //     (halves the dependent-MFMA chain depth: 8 -> 4) ---
        const u16* hp = h2 + (size_t)t * T_STRIDE + aLane;
        floatx4 a00 = {0.f, 0.f, 0.f, 0.f};
        floatx4 a01 = {0.f, 0.f, 0.f, 0.f};
        floatx4 a10 = {0.f, 0.f, 0.f, 0.f};
        floatx4 a11 = {0.f, 0.f, 0.f, 0.f};
        #pragma unroll
        for (int ks = 0; ks < 8; ks += 2) {
            bhalf8 x0 = ld8(hp + ks * WS_STRIDE);
            bhalf8 x1 = ld8(hp + (ks + 1) * WS_STRIDE);
            a00 = __builtin_amdgcn_mfma_f32_16x16x32_bf16(x0, bfrag[0][ks],     a00, 0, 0, 0);
            a10 = __builtin_amdgcn_mfma_f32_16x16x32_bf16(x0, bfrag[1][ks],     a10, 0, 0, 0);
            a01 = __builtin_amdgcn_mfma_f32_16x16x32_bf16(x1, bfrag[0][ks + 1], a01, 0, 0, 0);
            a11 = __builtin_amdgcn_mfma_f32_16x16x32_bf16(x1, bfrag[1][ks + 1], a11, 0, 0, 0);
        }
        floatx4 acc0 = a00 + a01;
        floatx4 acc1 = a10 + a11;
        float2 pj = *(const float2*)&proj[tok * H_ + colbase + c0];

        #pragma unroll
        for (int j = 0; j < 4; ++j) {    // D layout: row=(lq*4+j), col=l16
            red[wave][0][lq * 4 + j][l16] = acc0[j];
            red[wave][1][lq * 4 + j][l16] = acc1[j];
        }
        __syncthreads();

        // keep-alive for the touch (any waitcnt here is long covered)
        asm volatile("" :: "v"(touch_dummy));

        // --- reduce 4 waves + x_proj + fast tanh + bf16 tile store ---
        float z0 = red[0][c0 >> 4][row][c0 & 15] + red[1][c0 >> 4][row][c0 & 15]
                 + red[2][c0 >> 4][row][c0 & 15] + red[3][c0 >> 4][row][c0 & 15] + pj.x;
        float z1 = red[0][c1 >> 4][row][c1 & 15] + red[1][c1 >> 4][row][c1 & 15]
                 + red[2][c1 >> 4][row][c1 & 15] + red[3][c1 >> 4][row][c1 & 15] + pj.y;
        u32 pack = (u32)f2bf(fast_tanh(z0)) | ((u32)f2bf(fast_tanh(z1)) << 16);
        // wave stores contiguous 256B of the 1KB tile -> full-line writes,
        // hitting the lines pre-touched one step earlier
        *(u32*)&h2[(size_t)(t + 1) * T_STRIDE + sLane] = pack;

        // --- sync: drains all waves' h stores (vmcnt 0) + protects `red` ---
        __syncthreads();

        // --- publish: sc0 write-through store -> this XCD's L2 ---
        if (tid == 0)
            publish_flag_l2(myflag, t + 1);

        // --- per-wave wait on its 8 producer WGs via sc0+nt L2 reads ---
        if (t < S_ - 1) {
            const int target = t + 1;
            int spins = 0;
            for (;;) {
                int v = (lane < 8) ? poll_flag_l2(pollp) : 0x7fffffff;
                if (__all(v >= target)) break;
                if (++spins > SPIN_CAP) break;   // safety valve
            }
            asm volatile("" ::: "memory");   // no h-load hoist above the wait
        }
    }
}

// ---------------------------------------------------------------------------
// 4. output GEMM from h2: out[b][s][v] = dot(h2[s+1; b,:], W_ho[v,:]) + b_ho[v]
//    WG = (g, vblock, tchunk): 8 x 4 x 32 = 1024 WGs x 256 thr (4 WGs/CU:
//    four independent serial chains per CU overlap -> latency hiding).
// ---------------------------------------------------------------------------
__global__ __launch_bounds__(256) void out_gemm(
    const u16* __restrict__ h2, const u16* __restrict__ Who,
    const float* __restrict__ b_ho, float* __restrict__ out)
{
    const int wg = blockIdx.x;          // 1024
    const int g  = wg & 7;
    const int vb = (wg >> 3) & 3;
    const int tc = wg >> 5;             // 0..31
    const int tid = threadIdx.x;
    const int wave = tid >> 6;
    const int lane = tid & 63;
    const int l16 = lane & 15, lq = lane >> 4;
    const int v = vb * 64 + wave * 16 + l16;   // this lane's vocab column

    // W_ho slice, full K: 32 k-steps
    bhalf8 bw[32];
    #pragma unroll
    for (int ks = 0; ks < 32; ++ks)
        bw[ks] = ld8(&Who[(size_t)v * H_ + ks * 32 + lq * 8]);
    const float bias = b_ho[v];

    const int aLane = g * G_STRIDE + l16 * 32 + lq * 8;
    size_t oRow[4];
    #pragma unroll
    for (int j = 0; j < 4; ++j)
        oRow[j] = ((size_t)(g * 16 + lq * 4 + j) << 18) + v;

    for (int t = tc * 32; t < tc * 32 + 32; ++t) {
        const u16* hp = h2 + (size_t)(t + 1) * T_STRIDE + aLane;
        floatx4 accE = {0.f, 0.f, 0.f, 0.f};
        floatx4 accO = {0.f, 0.f, 0.f, 0.f};
        #pragma unroll
        for (int ks = 0; ks < 32; ks += 2) {
            bhalf8 a0 = ld8(hp + ks * WS_STRIDE);
            bhalf8 a1 = ld8(hp + ks * WS_STRIDE + WS_STRIDE);
            accE = __builtin_amdgcn_mfma_f32_16x16x32_bf16(a0, bw[ks],     accE, 0, 0, 0);
            accO = __builtin_amdgcn_mfma_f32_16x16x32_bf16(a1, bw[ks + 1], accO, 0, 0, 0);
        }
        #pragma unroll
        for (int j = 0; j < 4; ++j) {
            float z = accE[j] + accO[j] + bias;
            __builtin_nontemporal_store(z, &out[oRow[j] + (size_t)t * V_]);
        }
    }
}

// ---------------------------------------------------------------------------
// 5. h_final: d_out tail = fp32(h2[1024])
// ---------------------------------------------------------------------------
__global__ __launch_bounds__(256) void hfinal(const u16* __restrict__ h2,
                                              float* __restrict__ out)
{
    int i = blockIdx.x * 256 + threadIdx.x;   // 131072
    int b = i >> 10, k = i & 1023;
    int g = b >> 4, r = b & 15, ws = k >> 5, c = k & 31;
    out[33554432 + i] =
        bf2f(h2[(size_t)1024 * T_STRIDE + g * G_STRIDE + ws * WS_STRIDE + r * 32 + c]);
}

// ---------------------------------------------------------------------------
extern "C" void kernel_launch(void* const* d_in, const int* in_sizes, int n_in,
                              void* d_out, int out_size, void* d_ws, size_t ws_size,
                              hipStream_t stream) {
    const int*   seq    = (const int*)  d_in[0];
    const float* hidden = (const float*)d_in[1];
    const float* emb    = (const float*)d_in[2];
    const float* W_ih   = (const float*)d_in[3];
    const float* b_ih   = (const float*)d_in[4];
    const float* W_hh   = (const float*)d_in[5];
    const float* b_hh   = (const float*)d_in[6];
    const float* W_ho   = (const float*)d_in[7];
    const float* b_ho   = (const float*)d_in[8];
    float* out = (float*)d_out;

    char* ws = (char*)d_ws;
    u16*   h2     = (u16*)ws;
    u16*   Whh_bf = (u16*)(ws + WHH_OFF);
    u16*   Who_bf = (u16*)(ws + WHO_OFF);
    float* proj   = (float*)(ws + PROJ_OFF);
    int*   cnt    = (int*)(ws + CNT_OFF);

    prep_kernel<<<5648, 256, 0, stream>>>(W_hh, W_ho, hidden, Whh_bf, Who_bf, h2, cnt);
    proj_kernel<<<256, 256, 0, stream>>>(emb, W_ih, b_ih, b_hh, proj);
    rnn_seq<<<256, 256, 0, stream>>>(seq, proj, Whh_bf, h2, cnt);
    out_gemm<<<1024, 256, 0, stream>>>(h2, Who_bf, b_ho, out);
    hfinal<<<512, 256, 0, stream>>>(h2, out);
}

// Round 28
// 1629.841 us; speedup vs baseline: 1.0305x; 1.0305x over previous
//
#include <hip/hip_runtime.h>

// ---------------------------------------------------------------------------
// VanillaRNN on MI355X (gfx950)   [R28 = R26 revert: measured best (1632us).
//                                  R27's two levers both regressed: 4-chain
//                                  MFMA ILP (+10us; chain already hidden) and
//                                  out_gemm 4 WGs/CU (+35us; BW contention
//                                  past 2/CU). Final configuration:
//                                  - tile h2 layout (full-line writes)
//                                  - 4-wave K-split + LDS reduce
//                                  - sc0/nt XCD-L2 flags
//                                  - fast_tanh
//                                  - t+2 pre-touch (store-miss -> L2 hit)
//                                  - out_gemm 512 WGs (2/CU)]
// B=128, S=1024, H=1024, E=512, V=256
// ---------------------------------------------------------------------------

typedef __attribute__((ext_vector_type(8))) short bhalf8;   // 8 bf16 (4 VGPR)
typedef __attribute__((ext_vector_type(4))) float floatx4;  // 4 f32

typedef unsigned short u16;
typedef unsigned int u32;

#define B_  128
#define S_  1024
#define H_  1024
#define E_  512
#define V_  256

// h2 addressing (u16 units): idx(t,g,ws) = t*131072 + g*16384 + ws*512
#define T_STRIDE   131072        // 256KB / 2
#define G_STRIDE   16384         // 32KB / 2
#define WS_STRIDE  512           // 1KB / 2

// ws layout (bytes)
#define WHH_OFF       (268697600ull)            // h2: 1025*262144
#define WHO_OFF       (WHH_OFF + 2097152ull)
#define PROJ_OFF      (WHO_OFF + 524288ull)
#define CNT_OFF       (PROJ_OFF + 1048576ull)

#define FLAG_STRIDE   16                        // ints (64 B)
#define NFLAGS        4096
#define SPIN_CAP      16384                     // bounded spin: fail-loud

__device__ inline u16 f2bf(float f) {
    u32 u = __builtin_bit_cast(u32, f);
    u32 lsb = (u >> 16) & 1u;
    u += 0x7fffu + lsb;
    return (u16)(u >> 16);
}
__device__ inline float bf2f(u16 h) {
    u32 u = ((u32)h) << 16;
    return __builtin_bit_cast(float, u);
}
__device__ inline bhalf8 ld8(const u16* p) {
    return *(const bhalf8*)p;
}

// fast tanh: 1 - 2/(e^{2x}+1), e^{2x} = 2^{2*log2(e)*x}.
__device__ inline float fast_tanh(float x) {
    float t = __builtin_amdgcn_exp2f(2.885390082f * x);
    return 1.0f - 2.0f * __builtin_amdgcn_rcpf(t + 1.0f);
}

// Flag transport at the XCD's shared L2 (R11-proven):
__device__ inline int poll_flag_l2(const int* p) {
    int v;
    asm volatile("global_load_dword %0, %1, off sc0 nt\n\ts_waitcnt vmcnt(0)"
                 : "=v"(v) : "v"(p) : "memory");
    return v;
}
__device__ inline void publish_flag_l2(int* p, int v) {
    asm volatile("global_store_dword %0, %1, off sc0"
                 :: "v"(p), "v"(v) : "memory");
}

// ---------------------------------------------------------------------------
// 1. prep
// ---------------------------------------------------------------------------
__global__ __launch_bounds__(256) void prep_kernel(
    const float* __restrict__ W_hh, const float* __restrict__ W_ho,
    const float* __restrict__ hidden,
    u16* __restrict__ Whh_bf, u16* __restrict__ Who_bf,
    u16* __restrict__ h2, int* __restrict__ cnt)
{
    int i = blockIdx.x * 256 + threadIdx.x;
    if (i < 1048576) {
        Whh_bf[i] = f2bf(W_hh[i]);
    } else if (i < 1048576 + 262144) {
        int j = i - 1048576;
        Who_bf[j] = f2bf(W_ho[j]);
    } else if (i < 1048576 + 262144 + 131072) {
        int j = i - (1048576 + 262144);
        int b = j >> 10, k = j & 1023;
        int g = b >> 4, r = b & 15, ws = k >> 5, c = k & 31;
        h2[g * G_STRIDE + ws * WS_STRIDE + r * 32 + c] = f2bf(hidden[j]);
    } else if (i < 1048576 + 262144 + 131072 + NFLAGS) {
        cnt[i - (1048576 + 262144 + 131072)] = 0;
    }
}

// ---------------------------------------------------------------------------
// 2. proj table: proj[v][h] = b_ih[h] + b_hh[h] + sum_e emb[v][e]*W_ih[h][e]
// ---------------------------------------------------------------------------
__global__ __launch_bounds__(256) void proj_kernel(
    const float* __restrict__ emb, const float* __restrict__ W_ih,
    const float* __restrict__ b_ih, const float* __restrict__ b_hh,
    float* __restrict__ proj)
{
    __shared__ float er[E_];
    int v = blockIdx.x, tid = threadIdx.x;
    er[tid]       = emb[v * E_ + tid];
    er[tid + 256] = emb[v * E_ + 256 + tid];
    __syncthreads();
    const float4* x = (const float4*)er;
    #pragma unroll
    for (int j = 0; j < 4; ++j) {
        int hc = tid + j * 256;
        const float4* w = (const float4*)&W_ih[(size_t)hc * E_];
        float s = 0.f;
        #pragma unroll 8
        for (int e = 0; e < E_ / 4; ++e) {
            float4 ww = w[e]; float4 xx = x[e];
            s += ww.x * xx.x + ww.y * xx.y + ww.z * xx.z + ww.w * xx.w;
        }
        proj[v * H_ + hc] = s + b_ih[hc] + b_hh[hc];
    }
}

// ---------------------------------------------------------------------------
// 3. persistent sequential RNN kernel  (R25/R26-proven, byte-identical)
//    grid = 256 WGs x 256 threads. group g = wg&7 (XCD), 32 WGs/group,
//    WG owns 32 h-cols; 4 waves split K=1024; LDS reduce; tile store.
// ---------------------------------------------------------------------------
__global__ __launch_bounds__(256) void rnn_seq(
    const int* __restrict__ seq, const float* __restrict__ proj,
    const u16* __restrict__ Whh, u16* __restrict__ h2,
    int* __restrict__ cnt)
{
    const int wg = blockIdx.x;
    const int g = wg & 7;
    const int wslot = wg >> 3;          // 0..31 within group
    const int colbase = wslot * 32;
    const int tid = threadIdx.x;
    const int wave = tid >> 6;
    const int lane = tid & 63;
    const int l16 = lane & 15, lq = lane >> 4;
    const int kb = wave * 256;          // wave's K-slice base

    // W_hh slice resident in registers: 2 col-tiles x 8 k-steps
    bhalf8 bfrag[2][8];
    #pragma unroll
    for (int tt = 0; tt < 2; ++tt) {
        #pragma unroll
        for (int ks = 0; ks < 8; ++ks) {
            bfrag[tt][ks] = ld8(&Whh[(size_t)(colbase + tt * 16 + l16) * H_
                                     + kb + ks * 32 + lq * 8]);
        }
    }

    __shared__ float red[4][2][16][17];   // [wave][tile][row][col+pad]

    int* gflags = cnt + g * 32 * FLAG_STRIDE;
    int* myflag = gflags + wslot * FLAG_STRIDE;
    // wave w consumes h cols [w*256, w*256+256) = wslots [w*8, w*8+8)
    int* pollp  = gflags + (wave * 8 + (lane & 7)) * FLAG_STRIDE;

    // A-frag source: tile (t, g, wave*8+ks), lane offset l16*32 + lq*8
    const int aLane = g * G_STRIDE + wave * 8 * WS_STRIDE + l16 * 32 + lq * 8;

    // reduce-phase fixed indices (coalesced tile stores):
    const int row = tid >> 4;           // batch row within group (0..15)
    const int cp  = tid & 15;           // col pair (cols 2cp, 2cp+1)
    const int c0 = 2 * cp, c1 = c0 + 1;
    const int sLane = g * G_STRIDE + wslot * WS_STRIDE + row * 32 + cp * 2;
    const int seqBase = (g * 16 + row) * S_;

    // pre-touch target: 128B line `lane` (0..7) of this WG's output tile
    const int touchLane = g * G_STRIDE + wslot * WS_STRIDE + lane * 64;

    for (int t = 0; t < S_; ++t) {
        // early load (independent of h): token
        int tok = seq[seqBase + t];

        // --- pre-touch own output lines for step t+2 (stored at step t+1,
        //     ~5800cy from now -> fill guaranteed complete; no race). The
        //     allocation makes the t+1 store an L2 HIT: drain acks at L2
        //     and the consumer's read at t+1 is L2-served. Discarded result;
        //     keep-alive after sync1 (waitcnt covered by MFMA+LDS work). ---
        u32 touch_dummy = 0;
        if (wave == 0 && lane < 8 && t < S_ - 1) {
            const u16* tp = h2 + (size_t)(t + 2) * T_STRIDE + touchLane;
            asm volatile("global_load_dword %0, %1, off"
                         : "=v"(touch_dummy) : "v"(tp) : "memory");
        }

        // --- MFMA: z_partial[16 x 32] over this wave's K-slice ---
        const u16* hp = h2 + (size_t)t * T_STRIDE + aLane;
        floatx4 acc0 = {0.f, 0.f, 0.f, 0.f};
        floatx4 acc1 = {0.f, 0.f, 0.f, 0.f};
        #pragma unroll
        for (int ks = 0; ks < 8; ++ks) {
            bhalf8 a = ld8(hp + ks * WS_STRIDE);
            acc0 = __builtin_amdgcn_mfma_f32_16x16x32_bf16(a, bfrag[0][ks], acc0, 0, 0, 0);
            acc1 = __builtin_amdgcn_mfma_f32_16x16x32_bf16(a, bfrag[1][ks], acc1, 0, 0, 0);
        }
        float2 pj = *(const float2*)&proj[tok * H_ + colbase + c0];

        #pragma unroll
        for (int j = 0; j < 4; ++j) {    // D layout: row=(lq*4+j), col=l16
            red[wave][0][lq * 4 + j][l16] = acc0[j];
            red[wave][1][lq * 4 + j][l16] = acc1[j];
        }
        __syncthreads();

        // keep-alive for the touch (any waitcnt here is long covered)
        asm volatile("" :: "v"(touch_dummy));

        // --- reduce 4 waves + x_proj + fast tanh + bf16 tile store ---
        float z0 = red[0][c0 >> 4][row][c0 & 15] + red[1][c0 >> 4][row][c0 & 15]
                 + red[2][c0 >> 4][row][c0 & 15] + red[3][c0 >> 4][row][c0 & 15] + pj.x;
        float z1 = red[0][c1 >> 4][row][c1 & 15] + red[1][c1 >> 4][row][c1 & 15]
                 + red[2][c1 >> 4][row][c1 & 15] + red[3][c1 >> 4][row][c1 & 15] + pj.y;
        u32 pack = (u32)f2bf(fast_tanh(z0)) | ((u32)f2bf(fast_tanh(z1)) << 16);
        // wave stores contiguous 256B of the 1KB tile -> full-line writes,
        // hitting the lines pre-touched one step earlier
        *(u32*)&h2[(size_t)(t + 1) * T_STRIDE + sLane] = pack;

        // --- sync: drains all waves' h stores (vmcnt 0) + protects `red` ---
        __syncthreads();

        // --- publish: sc0 write-through store -> this XCD's L2 ---
        if (tid == 0)
            publish_flag_l2(myflag, t + 1);

        // --- per-wave wait on its 8 producer WGs via sc0+nt L2 reads ---
        if (t < S_ - 1) {
            const int target = t + 1;
            int spins = 0;
            for (;;) {
                int v = (lane < 8) ? poll_flag_l2(pollp) : 0x7fffffff;
                if (__all(v >= target)) break;
                if (++spins > SPIN_CAP) break;   // safety valve
            }
            asm volatile("" ::: "memory");   // no h-load hoist above the wait
        }
    }
}

// ---------------------------------------------------------------------------
// 4. output GEMM from h2: out[b][s][v] = dot(h2[s+1; b,:], W_ho[v,:]) + b_ho[v]
//    WG = (g, vblock, tchunk): 8 x 4 x 16 = 512 WGs x 256 thr (2 WGs/CU --
//    measured optimum: 1/CU = serial-latency-bound, 4/CU = BW contention).
// ---------------------------------------------------------------------------
__global__ __launch_bounds__(256) void out_gemm(
    const u16* __restrict__ h2, const u16* __restrict__ Who,
    const float* __restrict__ b_ho, float* __restrict__ out)
{
    const int wg = blockIdx.x;          // 512
    const int g  = wg & 7;
    const int vb = (wg >> 3) & 3;
    const int tc = wg >> 5;             // 0..15
    const int tid = threadIdx.x;
    const int wave = tid >> 6;
    const int lane = tid & 63;
    const int l16 = lane & 15, lq = lane >> 4;
    const int v = vb * 64 + wave * 16 + l16;   // this lane's vocab column

    // W_ho slice, full K: 32 k-steps
    bhalf8 bw[32];
    #pragma unroll
    for (int ks = 0; ks < 32; ++ks)
        bw[ks] = ld8(&Who[(size_t)v * H_ + ks * 32 + lq * 8]);
    const float bias = b_ho[v];

    const int aLane = g * G_STRIDE + l16 * 32 + lq * 8;
    size_t oRow[4];
    #pragma unroll
    for (int j = 0; j < 4; ++j)
        oRow[j] = ((size_t)(g * 16 + lq * 4 + j) << 18) + v;

    for (int t = tc * 64; t < tc * 64 + 64; ++t) {
        const u16* hp = h2 + (size_t)(t + 1) * T_STRIDE + aLane;
        floatx4 accE = {0.f, 0.f, 0.f, 0.f};
        floatx4 accO = {0.f, 0.f, 0.f, 0.f};
        #pragma unroll
        for (int ks = 0; ks < 32; ks += 2) {
            bhalf8 a0 = ld8(hp + ks * WS_STRIDE);
            bhalf8 a1 = ld8(hp + ks * WS_STRIDE + WS_STRIDE);
            accE = __builtin_amdgcn_mfma_f32_16x16x32_bf16(a0, bw[ks],     accE, 0, 0, 0);
            accO = __builtin_amdgcn_mfma_f32_16x16x32_bf16(a1, bw[ks + 1], accO, 0, 0, 0);
        }
        #pragma unroll
        for (int j = 0; j < 4; ++j) {
            float z = accE[j] + accO[j] + bias;
            __builtin_nontemporal_store(z, &out[oRow[j] + (size_t)t * V_]);
        }
    }
}

// ---------------------------------------------------------------------------
// 5. h_final: d_out tail = fp32(h2[1024])
// ---------------------------------------------------------------------------
__global__ __launch_bounds__(256) void hfinal(const u16* __restrict__ h2,
                                              float* __restrict__ out)
{
    int i = blockIdx.x * 256 + threadIdx.x;   // 131072
    int b = i >> 10, k = i & 1023;
    int g = b >> 4, r = b & 15, ws = k >> 5, c = k & 31;
    out[33554432 + i] =
        bf2f(h2[(size_t)1024 * T_STRIDE + g * G_STRIDE + ws * WS_STRIDE + r * 32 + c]);
}

// ---------------------------------------------------------------------------
extern "C" void kernel_launch(void* const* d_in, const int* in_sizes, int n_in,
                              void* d_out, int out_size, void* d_ws, size_t ws_size,
                              hipStream_t stream) {
    const int*   seq    = (const int*)  d_in[0];
    const float* hidden = (const float*)d_in[1];
    const float* emb    = (const float*)d_in[2];
    const float* W_ih   = (const float*)d_in[3];
    const float* b_ih   = (const float*)d_in[4];
    const float* W_hh   = (const float*)d_in[5];
    const float* b_hh   = (const float*)d_in[6];
    const float* W_ho   = (const float*)d_in[7];
    const float* b_ho   = (const float*)d_in[8];
    float* out = (float*)d_out;

    char* ws = (char*)d_ws;
    u16*   h2     = (u16*)ws;
    u16*   Whh_bf = (u16*)(ws + WHH_OFF);
    u16*   Who_bf = (u16*)(ws + WHO_OFF);
    float* proj   = (float*)(ws + PROJ_OFF);
    int*   cnt    = (int*)(ws + CNT_OFF);

    prep_kernel<<<5648, 256, 0, stream>>>(W_hh, W_ho, hidden, Whh_bf, Who_bf, h2, cnt);
    proj_kernel<<<256, 256, 0, stream>>>(emb, W_ih, b_ih, b_hh, proj);
    rnn_seq<<<256, 256, 0, stream>>>(seq, proj, Whh_bf, h2, cnt);
    out_gemm<<<512, 256, 0, stream>>>(h2, Who_bf, b_ho, out);
    hfinal<<<512, 256, 0, stream>>>(h2, out);
}